// Round 2
// baseline (1554.325 us; speedup 1.0000x reference)
//
#include <hip/hip_runtime.h>

#define BB 256
#define LL 65536
#define TS 1024
#define HIST 256
#define WINW 64
#define DIM 256
#define NPAT 64
#define TT 16

// Repack conv_w (d-major, [d][h]) into wQ[h4][d] = float4{w[d][4h4..4h4+3]}
// so the conv kernel reads coalesced float4 across d at fixed h4.
__global__ void prep_w(const float* __restrict__ w, float4* __restrict__ wQ) {
    int h4 = blockIdx.x;              // 0..63
    int d  = threadIdx.x;             // 0..255
    const float4* w4 = (const float4*)w;   // w[d][h] -> float4 index d*64 + h4
    wQ[h4 * DIM + d] = w4[d * (HIST / 4) + h4];
}

// Fused conv(stride 64, k=256, left-pad 255) + bias + relu + (hidden @ keys) + clip[0,6]
// One block = (batch b, tile of TT=16 output timesteps). 256 threads.
__launch_bounds__(256)
__global__ void scores_kernel(const float* __restrict__ x,
                              const float4* __restrict__ wQ,
                              const float* __restrict__ conv_b,
                              const float* __restrict__ keys,
                              float* __restrict__ scores) {
    __shared__ __align__(16) float xs[(TT - 1) * WINW + HIST];   // 1216 floats
    __shared__ float hid[TT * DIM];                              // 16 KB
    __shared__ float kch[64 * NPAT];                             // 16 KB keys chunk
    const int b   = blockIdx.y;
    const int t0  = blockIdx.x * TT;
    const int tid = threadIdx.x;

    // Stage x window [t0*64-255, t0*64+960] into LDS (zero left pad).
    const int base = t0 * WINW - (HIST - 1);
    for (int i = tid; i < (TT - 1) * WINW + HIST; i += 256) {
        int gi = base + i;
        xs[i] = (gi >= 0) ? x[(size_t)b * LL + gi] : 0.0f;
    }
    __syncthreads();

    // Conv: thread owns output channel d = tid, computes TT timesteps.
    float acc[TT];
#pragma unroll
    for (int tl = 0; tl < TT; ++tl) acc[tl] = 0.0f;
    const int d = tid;
    for (int h4 = 0; h4 < HIST / 4; ++h4) {
        float4 wv = wQ[h4 * DIM + d];          // coalesced, L2-resident (256 KB)
#pragma unroll
        for (int tl = 0; tl < TT; ++tl) {
            const float4 xv = *(const float4*)&xs[tl * WINW + h4 * 4];  // broadcast
            acc[tl] = fmaf(wv.x, xv.x, acc[tl]);
            acc[tl] = fmaf(wv.y, xv.y, acc[tl]);
            acc[tl] = fmaf(wv.z, xv.z, acc[tl]);
            acc[tl] = fmaf(wv.w, xv.w, acc[tl]);
        }
    }
    const float bias = conv_b[d];
#pragma unroll
    for (int tl = 0; tl < TT; ++tl)
        hid[tl * DIM + d] = fmaxf(acc[tl] + bias, 0.0f);

    // Scores: thread = (p = tid&63, tg = tid>>6), owns tl = tg + 4j, j=0..3.
    float sacc[4] = {0.f, 0.f, 0.f, 0.f};
    const int p = tid & 63, tg = tid >> 6;
    for (int dc = 0; dc < DIM; dc += 64) {
        __syncthreads();   // hid ready (first iter) / previous kch reads done
        for (int i = tid; i < 64 * NPAT; i += 256)
            kch[i] = keys[dc * NPAT + i];
        __syncthreads();
        for (int dl = 0; dl < 64; ++dl) {
            float kv = kch[dl * NPAT + p];     // conflict-free row read
#pragma unroll
            for (int j = 0; j < 4; ++j)
                sacc[j] = fmaf(hid[(tg + 4 * j) * DIM + dc + dl], kv, sacc[j]);
        }
    }
#pragma unroll
    for (int j = 0; j < 4; ++j) {
        int tl = tg + 4 * j;
        float s = fminf(fmaxf(sacc[j], 0.0f), 6.0f);   // relu6
        scores[((size_t)b * TS + t0 + tl) * NPAT + p] = s;
    }
}

// Sequential softmax scan per batch: avg += softmax(s - avg) - 1/NPAT.
// One wave (64 lanes = 64 patterns) per batch. Exact max-subtracted softmax.
__launch_bounds__(64)
__global__ void scan_kernel(const float* __restrict__ scores,
                            const float* __restrict__ avg0,
                            float* __restrict__ probs) {
    const int b = blockIdx.x;
    const int p = threadIdx.x;
    float avg = avg0[b * NPAT + p];
    const float inv = 1.0f / NPAT;
    const float* sc = scores + (size_t)b * TS * NPAT;
    float* pr = probs + (size_t)b * TS * NPAT;
    float s_next = sc[p];
    for (int t = 0; t < TS; ++t) {
        float s = s_next;
        if (t + 1 < TS) s_next = sc[(size_t)(t + 1) * NPAT + p];  // prefetch
        float z = s - avg;
        float m = z;
#pragma unroll
        for (int off = 32; off >= 1; off >>= 1)
            m = fmaxf(m, __shfl_xor(m, off, 64));
        float e = exp2f((z - m) * 1.44269504f);
        float sum = e;
#pragma unroll
        for (int off = 32; off >= 1; off >>= 1)
            sum += __shfl_xor(sum, off, 64);
        float prob = e / sum;
        pr[(size_t)t * NPAT + p] = prob;
        avg += prob - inv;
    }
}

// signal[b,t,w] = sum_p probs[b,t,p]*shapes[p,w]; out = relu(signal - x).
// Block = (b, 64 timesteps). 256 threads: w = tid&63, tg = tid>>6 covers 16 tl each.
__launch_bounds__(256)
__global__ void signal_kernel(const float* __restrict__ probs,
                              const float* __restrict__ shapes,
                              const float* __restrict__ x,
                              float* __restrict__ out) {
    __shared__ float sh[NPAT * WINW];   // 16 KB
    __shared__ float pt[64 * NPAT];     // 16 KB (64 timesteps of probs)
    const int b   = blockIdx.y;
    const int t0  = blockIdx.x * 64;
    const int tid = threadIdx.x;
    for (int i = tid; i < NPAT * WINW; i += 256) sh[i] = shapes[i];
    for (int i = tid; i < 64 * NPAT; i += 256)
        pt[i] = probs[((size_t)b * TS + t0) * NPAT + i];
    __syncthreads();
    const int w = tid & 63, tg = tid >> 6;
    float acc[16];
#pragma unroll
    for (int k = 0; k < 16; ++k) acc[k] = 0.0f;
    for (int pp = 0; pp < NPAT; ++pp) {
        float sv = sh[pp * WINW + w];          // conflict-free
#pragma unroll
        for (int k = 0; k < 16; ++k)
            acc[k] = fmaf(pt[(tg + 4 * k) * NPAT + pp], sv, acc[k]);
    }
#pragma unroll
    for (int k = 0; k < 16; ++k) {
        int tl = tg + 4 * k;
        size_t gi = (size_t)b * LL + (size_t)(t0 + tl) * WINW + w;
        out[gi] = fmaxf(acc[k] - x[gi], 0.0f);
    }
}

extern "C" void kernel_launch(void* const* d_in, const int* in_sizes, int n_in,
                              void* d_out, int out_size, void* d_ws, size_t ws_size,
                              hipStream_t stream) {
    const float* x      = (const float*)d_in[0];
    const float* avg0   = (const float*)d_in[1];
    const float* conv_w = (const float*)d_in[2];
    const float* conv_b = (const float*)d_in[3];
    const float* keys   = (const float*)d_in[4];
    const float* shapes = (const float*)d_in[5];
    float* out = (float*)d_out;

    char* ws = (char*)d_ws;
    float4* wQ    = (float4*)ws;                         // 256 KB
    float* scores = (float*)(ws + (256 << 10));          // 64 MB
    float* probs  = (float*)(ws + (256 << 10) + (size_t)BB * TS * NPAT * 4);  // 64 MB

    prep_w<<<dim3(HIST / 4), dim3(DIM), 0, stream>>>(conv_w, wQ);
    dim3 g1(TS / TT, BB);
    scores_kernel<<<g1, dim3(256), 0, stream>>>(x, wQ, conv_b, keys, scores);
    scan_kernel<<<dim3(BB), dim3(64), 0, stream>>>(scores, avg0, probs);
    dim3 g3(TS / 64, BB);
    signal_kernel<<<g3, dim3(256), 0, stream>>>(probs, shapes, x, out);
}

// Round 3
// 474.805 us; speedup vs baseline: 3.2736x; 3.2736x over previous
//
#include <hip/hip_runtime.h>

#define BB 256
#define LL 65536
#define TS 1024
#define HIST 256
#define WINW 64
#define DIM 256
#define NPAT 64

typedef short s8v __attribute__((ext_vector_type(8)));
typedef float f4v __attribute__((ext_vector_type(4)));

#define MFMA16(a, b, c) __builtin_amdgcn_mfma_f32_16x16x32_bf16((a), (b), (c), 0, 0, 0)

// ---- fp32 -> bf16 hi/lo split (combined error ~2^-18 relative) ----
__device__ __forceinline__ short bf16rne(float f) {
    unsigned u = __float_as_uint(f);
    unsigned r = (u + 0x7fffu + ((u >> 16) & 1u)) >> 16;
    return (short)r;
}
__device__ __forceinline__ float bf16tof(short h) {
    return __uint_as_float(((unsigned)(unsigned short)h) << 16);
}
__device__ __forceinline__ void split2(float f, short& hi, short& lo) {
    hi = bf16rne(f);
    lo = bf16rne(f - bf16tof(hi));
}

// ---- prep: conv_w[d][h] -> wF[kt*4+q][d][j] (B-frag layout, k=h, n=d), hi/lo ----
__global__ void prep_wf(const float* __restrict__ w, short* __restrict__ wFH,
                        short* __restrict__ wFL) {
    int idx = blockIdx.x * 256 + threadIdx.x;     // 8192 = 32 qk * 256 d
    int d = idx & 255, qk = idx >> 8;             // qk = kt*4+q, h0 = qk*8
    int h0 = qk * 8;
    s8v hv, lv;
#pragma unroll
    for (int j = 0; j < 8; ++j) {
        short h, l; split2(w[d * HIST + h0 + j], h, l);
        hv[j] = h; lv[j] = l;
    }
    *(s8v*)(wFH + (size_t)idx * 8) = hv;
    *(s8v*)(wFL + (size_t)idx * 8) = lv;
}

// ---- prep: keys[d][p] -> kF[kt*4+q][p][j] (k=d, n=p), hi/lo ----
__global__ void prep_keysf(const float* __restrict__ keys, short* __restrict__ kFH,
                           short* __restrict__ kFL) {
    int idx = blockIdx.x * 256 + threadIdx.x;     // 2048 = 32 qk * 64 p
    int p = idx & 63, qk = idx >> 6;
    int d0 = qk * 8;
    s8v hv, lv;
#pragma unroll
    for (int j = 0; j < 8; ++j) {
        short h, l; split2(keys[(d0 + j) * NPAT + p], h, l);
        hv[j] = h; lv[j] = l;
    }
    *(s8v*)(kFH + (size_t)idx * 8) = hv;
    *(s8v*)(kFL + (size_t)idx * 8) = lv;
}

// ---- prep: shapes[p][w] -> sF[kt*4+q][w][j] (k=p, n=w), hi/lo ----
__global__ void prep_shapesf(const float* __restrict__ sh, short* __restrict__ sFH,
                             short* __restrict__ sFL) {
    int idx = blockIdx.x * 256 + threadIdx.x;     // 512 = 8 qk * 64 w
    int w = idx & 63, qk = idx >> 6;
    int p0 = qk * 8;
    s8v hv, lv;
#pragma unroll
    for (int j = 0; j < 8; ++j) {
        short h, l; split2(sh[(p0 + j) * WINW + w], h, l);
        hv[j] = h; lv[j] = l;
    }
    *(s8v*)(sFH + (size_t)idx * 8) = hv;
    *(s8v*)(sFL + (size_t)idx * 8) = lv;
}

#define WELEM 2240           // 31*64 + 256 window elements
#define WUNIT 280            // WELEM/8
#define HPAD 264             // hid row stride (256 + 8 for bank decorrelation)

__device__ __forceinline__ int swz(int u) { return u ^ ((u >> 3) & 7); }

// ---- fused conv + relu + (hid @ keys) + relu6, MFMA split-bf16 ----
// block = (32 timesteps, one batch); 256 threads = 4 waves.
__launch_bounds__(256, 2)
__global__ void scores_mfma(const float* __restrict__ x,
                            const short* __restrict__ wFH, const short* __restrict__ wFL,
                            const short* __restrict__ kFH, const short* __restrict__ kFL,
                            const float* __restrict__ conv_b,
                            float* __restrict__ scores) {
    __shared__ __align__(16) short xsH[WUNIT * 8], xsL[WUNIT * 8];
    __shared__ __align__(16) short hidH[32 * HPAD], hidL[32 * HPAD];

    const int b = blockIdx.y, t0 = blockIdx.x * 32;
    const int tid = threadIdx.x;
    const int lane = tid & 63, wid = tid >> 6;
    const int m = lane & 15, q = lane >> 4;

    // Stage x window as swizzled bf16 hi/lo. A[mrow][k] = x[t0*64-255 + mrow*64 + k]
    const float* xb = x + (size_t)b * LL;
    const int gbase = t0 * WINW - (HIST - 1);
    for (int i = tid; i < WELEM; i += 256) {
        int gi = gbase + i;
        float v = (gi >= 0) ? xb[gi] : 0.0f;
        short h, l; split2(v, h, l);
        int pos = (swz(i >> 3) << 3) | (i & 7);
        xsH[pos] = h; xsL[pos] = l;
    }
    __syncthreads();

    // Phase 1: conv GEMM. Wave wid owns d-range [wid*64, wid*64+64).
    const int nb = wid * 64;
    f4v acc[2][4];
#pragma unroll
    for (int mt = 0; mt < 2; ++mt)
#pragma unroll
        for (int nt = 0; nt < 4; ++nt) acc[mt][nt] = (f4v)0.0f;

    for (int kt = 0; kt < 8; ++kt) {
        s8v aH[2], aL[2];
#pragma unroll
        for (int mt = 0; mt < 2; ++mt) {
            int row = mt * 16 + m;
            int su = swz(row * 8 + kt * 4 + q) << 3;
            aH[mt] = *(const s8v*)&xsH[su];
            aL[mt] = *(const s8v*)&xsL[su];
        }
        s8v bH[4], bL[4];
#pragma unroll
        for (int nt = 0; nt < 4; ++nt) {
            size_t bi = ((size_t)(kt * 4 + q) * 256 + nb + nt * 16 + m) * 8;
            bH[nt] = *(const s8v*)(wFH + bi);
            bL[nt] = *(const s8v*)(wFL + bi);
        }
#pragma unroll
        for (int mt = 0; mt < 2; ++mt)
#pragma unroll
            for (int nt = 0; nt < 4; ++nt) {
                acc[mt][nt] = MFMA16(aH[mt], bH[nt], acc[mt][nt]);
                acc[mt][nt] = MFMA16(aL[mt], bH[nt], acc[mt][nt]);
                acc[mt][nt] = MFMA16(aH[mt], bL[nt], acc[mt][nt]);
            }
    }

    // Epilogue 1: bias + relu -> hid (bf16 hi/lo, padded rows)
#pragma unroll
    for (int mt = 0; mt < 2; ++mt)
#pragma unroll
        for (int nt = 0; nt < 4; ++nt) {
            int d = nb + nt * 16 + m;
            float bias = conv_b[d];
#pragma unroll
            for (int r = 0; r < 4; ++r) {
                int row = mt * 16 + q * 4 + r;
                float v = fmaxf(acc[mt][nt][r] + bias, 0.0f);
                short h, l; split2(v, h, l);
                hidH[row * HPAD + d] = h;
                hidL[row * HPAD + d] = l;
            }
        }
    __syncthreads();

    // Phase 2: scores GEMM (K=256 over d). Wave wid owns p-range [wid*16, +16).
    const int pb = wid * 16;
    f4v acc2[2];
    acc2[0] = (f4v)0.0f; acc2[1] = (f4v)0.0f;
    for (int kt = 0; kt < 8; ++kt) {
        s8v aH[2], aL[2];
#pragma unroll
        for (int mt = 0; mt < 2; ++mt) {
            int off = (mt * 16 + m) * HPAD + kt * 32 + q * 8;
            aH[mt] = *(const s8v*)&hidH[off];
            aL[mt] = *(const s8v*)&hidL[off];
        }
        size_t bi = ((size_t)(kt * 4 + q) * 64 + pb + m) * 8;
        s8v bH = *(const s8v*)(kFH + bi);
        s8v bL = *(const s8v*)(kFL + bi);
#pragma unroll
        for (int mt = 0; mt < 2; ++mt) {
            acc2[mt] = MFMA16(aH[mt], bH, acc2[mt]);
            acc2[mt] = MFMA16(aL[mt], bH, acc2[mt]);
            acc2[mt] = MFMA16(aH[mt], bL, acc2[mt]);
        }
    }
#pragma unroll
    for (int mt = 0; mt < 2; ++mt)
#pragma unroll
        for (int r = 0; r < 4; ++r) {
            int row = mt * 16 + q * 4 + r;
            float s = fminf(fmaxf(acc2[mt][r], 0.0f), 6.0f);
            scores[((size_t)b * TS + t0 + row) * NPAT + pb + m] = s;
        }
}

// ---- sequential softmax scan, DPP wave reduction ----
template <int CTRL>
__device__ __forceinline__ float dppadd(float x) {
    int t = __builtin_amdgcn_update_dpp(0, __float_as_int(x), CTRL, 0xf, 0xf, true);
    return x + __int_as_float(t);
}

__launch_bounds__(64)
__global__ void scan_kernel(const float* __restrict__ scores,
                            const float* __restrict__ avg0,
                            float* __restrict__ probs) {
    const int b = blockIdx.x, p = threadIdx.x;
    float avg = avg0[b * NPAT + p];
    const float inv = 1.0f / NPAT;
    const float* sc = scores + (size_t)b * TS * NPAT;
    float* pr = probs + (size_t)b * TS * NPAT;
    float s_next = sc[p];
    for (int t = 0; t < TS; ++t) {
        float s = s_next;
        if (t + 1 < TS) s_next = sc[(size_t)(t + 1) * NPAT + p];
        float z = (s - avg) * 1.44269504f;
        z = fminf(fmaxf(z, -115.0f), 115.0f);     // never binds in practice
        float e = exp2f(z);
        float v = e;                               // wave64 sum -> lane 63
        v = dppadd<0x111>(v);   // row_shr:1
        v = dppadd<0x112>(v);   // row_shr:2
        v = dppadd<0x114>(v);   // row_shr:4
        v = dppadd<0x118>(v);   // row_shr:8
        v = dppadd<0x142>(v);   // row_bcast:15
        v = dppadd<0x143>(v);   // row_bcast:31
        float tot = __int_as_float(__builtin_amdgcn_readlane(__float_as_int(v), 63));
        float prob = e * __builtin_amdgcn_rcpf(tot);
        pr[(size_t)t * NPAT + p] = prob;
        avg += prob - inv;
    }
}

// ---- signal = probs @ shapes (MFMA split-bf16), out = relu(signal - x) ----
// block = (64 timesteps, one batch); 256 threads = 4 waves (wave = 16-row m-tile).
__launch_bounds__(256)
__global__ void signal_mfma(const float* __restrict__ probs,
                            const short* __restrict__ sFH, const short* __restrict__ sFL,
                            const float* __restrict__ x,
                            float* __restrict__ out) {
    __shared__ __align__(16) short pH[64 * 72], pL[64 * 72];   // 72 = 64 + 8 pad
    const int b = blockIdx.y, t0 = blockIdx.x * 64;
    const int tid = threadIdx.x;
    const int lane = tid & 63, wid = tid >> 6;
    const int m = lane & 15, q = lane >> 4;

    const float* pbase = probs + ((size_t)b * TS + t0) * NPAT;
    for (int i = tid; i < 64 * 64; i += 256) {
        int r = i >> 6, c = i & 63;
        short h, l; split2(pbase[i], h, l);
        pH[r * 72 + c] = h; pL[r * 72 + c] = l;
    }
    __syncthreads();

    f4v acc[4];
#pragma unroll
    for (int nt = 0; nt < 4; ++nt) acc[nt] = (f4v)0.0f;

#pragma unroll
    for (int kt = 0; kt < 2; ++kt) {
        int off = (wid * 16 + m) * 72 + kt * 32 + q * 8;
        s8v aH = *(const s8v*)&pH[off];
        s8v aL = *(const s8v*)&pL[off];
#pragma unroll
        for (int nt = 0; nt < 4; ++nt) {
            size_t bi = ((size_t)(kt * 4 + q) * 64 + nt * 16 + m) * 8;
            s8v bH = *(const s8v*)(sFH + bi);
            s8v bL = *(const s8v*)(sFL + bi);
            acc[nt] = MFMA16(aH, bH, acc[nt]);
            acc[nt] = MFMA16(aL, bH, acc[nt]);
            acc[nt] = MFMA16(aH, bL, acc[nt]);
        }
    }
#pragma unroll
    for (int nt = 0; nt < 4; ++nt)
#pragma unroll
        for (int r = 0; r < 4; ++r) {
            int row = wid * 16 + q * 4 + r;
            int w = nt * 16 + m;
            size_t gi = (size_t)b * LL + (size_t)(t0 + row) * WINW + w;
            out[gi] = fmaxf(acc[nt][r] - x[gi], 0.0f);
        }
}

extern "C" void kernel_launch(void* const* d_in, const int* in_sizes, int n_in,
                              void* d_out, int out_size, void* d_ws, size_t ws_size,
                              hipStream_t stream) {
    const float* x      = (const float*)d_in[0];
    const float* avg0   = (const float*)d_in[1];
    const float* conv_w = (const float*)d_in[2];
    const float* conv_b = (const float*)d_in[3];
    const float* keys   = (const float*)d_in[4];
    const float* shapes = (const float*)d_in[5];
    float* out = (float*)d_out;

    char* ws = (char*)d_ws;
    size_t o = 0;
    float* scores = (float*)(ws + o); o += (size_t)BB * TS * NPAT * 4;   // 64 MB
    float* probs  = (float*)(ws + o); o += (size_t)BB * TS * NPAT * 4;   // 64 MB
    short* wFH = (short*)(ws + o); o += 8192 * 16;
    short* wFL = (short*)(ws + o); o += 8192 * 16;
    short* kFH = (short*)(ws + o); o += 2048 * 16;
    short* kFL = (short*)(ws + o); o += 2048 * 16;
    short* sFH = (short*)(ws + o); o += 512 * 16;
    short* sFL = (short*)(ws + o); o += 512 * 16;

    prep_wf<<<32, 256, 0, stream>>>(conv_w, wFH, wFL);
    prep_keysf<<<8, 256, 0, stream>>>(keys, kFH, kFL);
    prep_shapesf<<<2, 256, 0, stream>>>(shapes, sFH, sFL);

    scores_mfma<<<dim3(TS / 32, BB), 256, 0, stream>>>(x, wFH, wFL, kFH, kFL, conv_b, scores);
    scan_kernel<<<dim3(BB), 64, 0, stream>>>(scores, avg0, probs);
    signal_mfma<<<dim3(TS / 64, BB), 256, 0, stream>>>(probs, sFH, sFL, x, out);
}